// Round 7
// baseline (490.937 us; speedup 1.0000x reference)
//
#include <hip/hip_runtime.h>
#include <cstddef>

#define BB 8
#define NN 1024
#define KK 20
#define CCAT 169
#define NT 16  // n-tiles of 64 in final fused GEMM

// ---------------- neg dist, symmetric triangle tiles, norms fused in --------
__global__ __launch_bounds__(256) void dist_tile_kernel(
    const float* __restrict__ src, int bs, int F, float* __restrict__ dist) {
  __shared__ float As[8][128];
  __shared__ float Bs[8][128];
  int b = blockIdx.z;
  int rem = blockIdx.x, bi = 0;
  while (rem >= 8 - bi) { rem -= 8 - bi; ++bi; }
  int bj = bi + rem;
  int n0 = bi * 128;
  int m0 = bj * 128;
  int t = threadIdx.x;
  int tx = t & 15, ty = t >> 4;
  const float* p = src + (size_t)b * bs;

  float acc[8][8];
  float xn[8], xm[8];
#pragma unroll
  for (int i = 0; i < 8; ++i) {
    xn[i] = 0.f;
    xm[i] = 0.f;
#pragma unroll
    for (int j = 0; j < 8; ++j) acc[i][j] = 0.f;
  }

  int fr = t >> 5;
  int cc = (t & 31) << 2;
  for (int f0 = 0; f0 < F; f0 += 8) {
    int f = f0 + fr;
    float4 av = {0.f, 0.f, 0.f, 0.f}, bv = {0.f, 0.f, 0.f, 0.f};
    if (f < F) {
      av = *(const float4*)(p + (size_t)f * NN + n0 + cc);
      bv = *(const float4*)(p + (size_t)f * NN + m0 + cc);
    }
    __syncthreads();
    *(float4*)&As[fr][cc] = av;
    *(float4*)&Bs[fr][cc] = bv;
    __syncthreads();
#pragma unroll
    for (int f2 = 0; f2 < 8; ++f2) {
      float4 al = *(const float4*)&As[f2][ty << 2];
      float4 ah = *(const float4*)&As[f2][64 + (ty << 2)];
      float4 bl = *(const float4*)&Bs[f2][tx << 2];
      float4 bh = *(const float4*)&Bs[f2][64 + (tx << 2)];
      float a[8] = {al.x, al.y, al.z, al.w, ah.x, ah.y, ah.z, ah.w};
      float bb[8] = {bl.x, bl.y, bl.z, bl.w, bh.x, bh.y, bh.z, bh.w};
#pragma unroll
      for (int i = 0; i < 8; ++i) xn[i] += a[i] * a[i];
#pragma unroll
      for (int j = 0; j < 8; ++j) xm[j] += bb[j] * bb[j];
#pragma unroll
      for (int i = 0; i < 8; ++i)
#pragma unroll
        for (int j = 0; j < 8; ++j) acc[i][j] += a[i] * bb[j];
    }
  }

#pragma unroll
  for (int i = 0; i < 8; ++i)
#pragma unroll
    for (int j = 0; j < 8; ++j) acc[i][j] = 2.f * acc[i][j] - xn[i] - xm[j];

#pragma unroll
  for (int i = 0; i < 8; ++i) {
    int n = n0 + ((i < 4) ? ((ty << 2) + i) : (64 + (ty << 2) + i - 4));
    float* dr = dist + (((size_t)b * NN + n) << 10);
    *(float4*)(dr + m0 + (tx << 2)) =
        make_float4(acc[i][0], acc[i][1], acc[i][2], acc[i][3]);
    *(float4*)(dr + m0 + 64 + (tx << 2)) =
        make_float4(acc[i][4], acc[i][5], acc[i][6], acc[i][7]);
  }

  if (bi != bj) {
#pragma unroll
    for (int j = 0; j < 8; ++j) {
      int m = m0 + ((j < 4) ? ((tx << 2) + j) : (64 + (tx << 2) + j - 4));
      float* dr = dist + (((size_t)b * NN + m) << 10);
      *(float4*)(dr + n0 + (ty << 2)) =
          make_float4(acc[0][j], acc[1][j], acc[2][j], acc[3][j]);
      *(float4*)(dr + n0 + 64 + (ty << 2)) =
          make_float4(acc[4][j], acc[5][j], acc[6][j], acc[7][j]);
    }
  }
}

// ---------------- top-k (k=20) per row, one wave per row ----------------
__device__ __forceinline__ unsigned long long shfl_xor_u64(
    unsigned long long v, int off) {
  unsigned lo = (unsigned)v, hi = (unsigned)(v >> 32);
  lo = __shfl_xor(lo, off, 64);
  hi = __shfl_xor(hi, off, 64);
  return ((unsigned long long)hi << 32) | lo;
}

__global__ __launch_bounds__(256) void topk_kernel(
    const float* __restrict__ dist, int* __restrict__ idx_out) {
  int wave = threadIdx.x >> 6;
  int lane = threadIdx.x & 63;
  int row = blockIdx.x * 4 + wave;
  const float* d = dist + ((size_t)row << 10);

  unsigned long long key[16];
#pragma unroll
  for (int s = 0; s < 16; ++s) {
    int m = lane + (s << 6);
    unsigned u = __float_as_uint(d[m]);
    u = (u & 0x80000000u) ? ~u : (u | 0x80000000u);
    key[s] = ((unsigned long long)u << 32) | (unsigned)(NN - 1 - m);
  }

#pragma unroll
  for (int size = 2; size <= 16; size <<= 1) {
#pragma unroll
    for (int stride = size >> 1; stride > 0; stride >>= 1) {
#pragma unroll
      for (int i = 0; i < 16; ++i) {
        int j = i ^ stride;
        if (j > i) {
          unsigned long long a = key[i], c = key[j];
          bool desc = ((i & size) == 0);
          bool sw = desc ? (a < c) : (a > c);
          key[i] = sw ? c : a;
          key[j] = sw ? a : c;
        }
      }
    }
  }

  int* out = idx_out + row * KK;
  unsigned long long head = key[0];
  for (int r = 0; r < KK; ++r) {
    unsigned long long w = head;
#pragma unroll
    for (int off = 32; off > 0; off >>= 1) {
      unsigned long long o = shfl_xor_u64(w, off);
      if (o > w) w = o;
    }
    if (lane == 0) out[r] = (NN - 1) - (int)(w & 0xFFFFFFFFull);
    if (head == w) {
#pragma unroll
      for (int s = 0; s < 15; ++s) key[s] = key[s + 1];
      key[15] = 0ull;
      head = key[0];
    }
  }
}

// ---------------- VN transform as a proper tiled GEMM ----------------
// For all (b,o,g): uf=sum_i wfa[o][i]*src[i][g], vf with wfb=Wf[o][D+i]-wfa,
// ud/vd likewise from Wd. Output float2 {uf,ud} -> ubuf[(b*Co+o)*3072+g],
// {vf,vd} -> vbuf. K-accumulation i-ascending == original edge phase A order.
// Tile: 16 o x 128 g, BK=16.
__global__ __launch_bounds__(256) void transform_kernel(
    const float* __restrict__ src, int bs, int D, int Co,
    const float* __restrict__ Wf, const float* __restrict__ Wd,
    float2* __restrict__ ubuf, float2* __restrict__ vbuf) {
  __shared__ float4 Slds4[16][32];  // [k][g/4]  8 KB
  __shared__ float4 Wlds[16][16];   // [i][o] = (wfa,wfb,wda,wdb)  4 KB
  int b = blockIdx.z;
  int g0 = blockIdx.x * 128;
  int o0 = blockIdx.y * 16;
  int t = threadIdx.x;
  int tx = t & 15, ty = t >> 4;
  const float* sb = src + (size_t)b * bs;

  float uf[8], ud[8], vf[8], vd[8];
#pragma unroll
  for (int g = 0; g < 8; ++g) { uf[g] = 0.f; ud[g] = 0.f; vf[g] = 0.f; vd[g] = 0.f; }

  for (int f0 = 0; f0 < D; f0 += 16) {
    // stage W: thread (tx=i_local, ty=o_local)
    float4 w4 = {0.f, 0.f, 0.f, 0.f};
    {
      int i = f0 + tx;
      int o = o0 + ty;
      if (i < D && o < Co) {
        float wfa = Wf[o * 2 * D + i];
        float wfb = Wf[o * 2 * D + D + i];
        float wda = Wd[o * 2 * D + i];
        float wdb = Wd[o * 2 * D + D + i];
        w4 = make_float4(wfa, wfb - wfa, wda, wdb - wda);
      }
    }
    // stage S: 512 float4 over [16][128], 2 per thread
    int q0 = t, q1 = t + 256;
    int r0 = q0 >> 5, c0 = q0 & 31;
    int r1 = q1 >> 5, c1 = q1 & 31;
    float4 s0 = {0.f, 0.f, 0.f, 0.f}, s1 = {0.f, 0.f, 0.f, 0.f};
    if (f0 + r0 < D)
      s0 = *(const float4*)(sb + (size_t)(f0 + r0) * 3 * NN + g0 + (c0 << 2));
    if (f0 + r1 < D)
      s1 = *(const float4*)(sb + (size_t)(f0 + r1) * 3 * NN + g0 + (c1 << 2));
    __syncthreads();
    Wlds[tx][ty] = w4;
    Slds4[r0][c0] = s0;
    Slds4[r1][c1] = s1;
    __syncthreads();
#pragma unroll
    for (int k = 0; k < 16; ++k) {
      float4 w = Wlds[k][ty];
      float4 sA = Slds4[k][tx << 1];
      float4 sB = Slds4[k][(tx << 1) + 1];
      float sg[8] = {sA.x, sA.y, sA.z, sA.w, sB.x, sB.y, sB.z, sB.w};
#pragma unroll
      for (int g = 0; g < 8; ++g) {
        uf[g] += w.x * sg[g];
        vf[g] += w.y * sg[g];
        ud[g] += w.z * sg[g];
        vd[g] += w.w * sg[g];
      }
    }
    __syncthreads();
  }

  int o = o0 + ty;
  if (o < Co) {
    size_t base = ((size_t)b * Co + o) * 3072 + g0 + (tx << 3);  // float2 units
    float4* up = (float4*)(ubuf + base);
    float4* vp = (float4*)(vbuf + base);
#pragma unroll
    for (int g2 = 0; g2 < 4; ++g2) {
      up[g2] = make_float4(uf[2 * g2], ud[2 * g2], uf[2 * g2 + 1], ud[2 * g2 + 1]);
      vp[g2] = make_float4(vf[2 * g2], vd[2 * g2], vf[2 * g2 + 1], vd[2 * g2 + 1]);
    }
  }
}

// ---------------- gather + VN nonlinearity + mean over k ----------------
// Loads precomputed U,V rows (24 KB each) into LDS, then the k=20 gather.
// blockIdx.y = n-slice (duplication cost is just the LDS fill now).
__global__ __launch_bounds__(256) void gather_kernel(
    const float2* __restrict__ ubuf, const float2* __restrict__ vbuf, int Co,
    int nsplit, const int* __restrict__ idx, int ooff,
    float* __restrict__ xcat) {
  __shared__ float4 U4[1536];  // 24 KB
  __shared__ float4 V4[1536];  // 24 KB
  int bo = blockIdx.x;
  int b = bo / Co, o = bo % Co;
  int t = threadIdx.x;
  const float4* usrc = (const float4*)(ubuf + ((size_t)b * Co + o) * 3072);
  const float4* vsrc = (const float4*)(vbuf + ((size_t)b * Co + o) * 3072);
#pragma unroll
  for (int r = 0; r < 6; ++r) {
    U4[t + 256 * r] = usrc[t + 256 * r];
    V4[t + 256 * r] = vsrc[t + 256 * r];
  }
  __syncthreads();
  const float2* Ulds = (const float2*)U4;
  const float2* Vlds = (const float2*)V4;

  const float inv_k = 1.f / KK;
  int cnt = NN / nsplit;
  int nbase = blockIdx.y * cnt;
  for (int n = nbase + t; n < nbase + cnt; n += 256) {
    float2 v0 = Vlds[n];
    float2 v1 = Vlds[NN + n];
    float2 v2 = Vlds[2 * NN + n];
    const int4* ip = (const int4*)(idx + (b * NN + n) * KK);
    float a0 = 0.f, a1 = 0.f, a2 = 0.f;
#pragma unroll
    for (int q = 0; q < 5; ++q) {
      int4 iv = ip[q];
      int nbs[4] = {iv.x, iv.y, iv.z, iv.w};
#pragma unroll
      for (int jj = 0; jj < 4; ++jj) {
        int nb = nbs[jj];
        float2 u0 = Ulds[nb];
        float2 u1 = Ulds[NN + nb];
        float2 u2 = Ulds[2 * NN + nb];
        float pf0 = u0.x + v0.x, pd0 = u0.y + v0.y;
        float pf1 = u1.x + v1.x, pd1 = u1.y + v1.y;
        float pf2 = u2.x + v2.x, pd2 = u2.y + v2.y;
        float dot = pf0 * pd0 + pf1 * pd1 + pf2 * pd2;
        float dsq = pd0 * pd0 + pd1 * pd1 + pd2 * pd2;
        float g = (dot >= 0.f) ? 0.f : 0.8f * dot / (dsq + 1e-6f);
        a0 += pf0 - g * pd0;
        a1 += pf1 - g * pd1;
        a2 += pf2 - g * pd2;
      }
    }
    size_t ob = (size_t)b * CCAT * 3 * NN + (size_t)(ooff + o) * 3 * NN + n;
    xcat[ob] = a0 * inv_k;
    xcat[ob + NN] = a1 * inv_k;
    xcat[ob + 2 * NN] = a2 * inv_k;
  }
}

// ---------------- fused final GEMM + dvec + VN-leakyrelu + partial n-sum ----
// o-tile 32 (grid y=11): 1408 blocks = 5.5 blocks/CU = ~22 waves/CU, double
// R0's latency hiding. Thread tile 2o x 4n x 3c. Same accumulation order.
__global__ __launch_bounds__(256) void final_fused_kernel(
    const float* __restrict__ xcat, const float* __restrict__ Wf4,
    const float* __restrict__ Wd4, float* __restrict__ part) {
  __shared__ float Ws[16][32];
  __shared__ float Xs[3][16][64];
  __shared__ float Wds[16];
  int b = blockIdx.z;
  int o0 = blockIdx.y * 32;
  int n0 = blockIdx.x * 64;
  int t = threadIdx.x;
  int tx = t & 15, ty = t >> 4;

  float acc[3][2][4];  // [c][o_i][n_j]
  float dv[3][4];      // [c][n_j]
#pragma unroll
  for (int c = 0; c < 3; ++c) {
#pragma unroll
    for (int i = 0; i < 2; ++i)
#pragma unroll
      for (int j = 0; j < 4; ++j) acc[c][i][j] = 0.f;
#pragma unroll
    for (int j = 0; j < 4; ++j) dv[c][j] = 0.f;
  }

  const float* xb = xcat + (size_t)b * CCAT * 3 * NN;
  for (int f0 = 0; f0 < CCAT; f0 += 16) {
    int f = f0 + ty;
    float4 xv[3];
#pragma unroll
    for (int c = 0; c < 3; ++c) {
      xv[c] = make_float4(0.f, 0.f, 0.f, 0.f);
      if (f < CCAT)
        xv[c] = *(const float4*)(xb + ((size_t)f * 3 + c) * NN + n0 + (tx << 2));
    }
    // W: thread (ty=f_local, tx=o_col) loads cols tx and tx+16
    float wv0 = 0.f, wv1 = 0.f;
    {
      int oa = o0 + tx, ob = o0 + tx + 16;
      if (f < CCAT) {
        if (oa < 341) wv0 = Wf4[oa * CCAT + f];
        if (ob < 341) wv1 = Wf4[ob * CCAT + f];
      }
    }
    float wdv = 0.f;
    if (t < 16 && f0 + t < CCAT) wdv = Wd4[f0 + t];
    __syncthreads();
#pragma unroll
    for (int c = 0; c < 3; ++c) *(float4*)&Xs[c][ty][tx << 2] = xv[c];
    Ws[ty][tx] = wv0;
    Ws[ty][tx + 16] = wv1;
    if (t < 16) Wds[t] = wdv;
    __syncthreads();
#pragma unroll
    for (int f2 = 0; f2 < 16; ++f2) {
      float2 w = *(const float2*)&Ws[f2][ty << 1];
      float wd = Wds[f2];
#pragma unroll
      for (int c = 0; c < 3; ++c) {
        float4 x = *(const float4*)&Xs[c][f2][tx << 2];
        float xa[4] = {x.x, x.y, x.z, x.w};
#pragma unroll
        for (int j = 0; j < 4; ++j) dv[c][j] += wd * xa[j];
#pragma unroll
        for (int j = 0; j < 4; ++j) {
          acc[c][0][j] += w.x * xa[j];
          acc[c][1][j] += w.y * xa[j];
        }
      }
    }
  }

  float s[3][2];
#pragma unroll
  for (int c = 0; c < 3; ++c)
#pragma unroll
    for (int i = 0; i < 2; ++i) s[c][i] = 0.f;
#pragma unroll
  for (int i = 0; i < 2; ++i) {
#pragma unroll
    for (int j = 0; j < 4; ++j) {
      float d0 = dv[0][j], d1 = dv[1][j], d2 = dv[2][j];
      float p0 = acc[0][i][j], p1 = acc[1][i][j], p2 = acc[2][i][j];
      float dot = p0 * d0 + p1 * d1 + p2 * d2;
      float dsq = d0 * d0 + d1 * d1 + d2 * d2;
      float g = (dot >= 0.f) ? 0.f : 0.8f * dot / (dsq + 1e-6f);
      s[0][i] += p0 - g * d0;
      s[1][i] += p1 - g * d1;
      s[2][i] += p2 - g * d2;
    }
  }

#pragma unroll
  for (int off = 1; off < 16; off <<= 1) {
#pragma unroll
    for (int c = 0; c < 3; ++c)
#pragma unroll
      for (int i = 0; i < 2; ++i) s[c][i] += __shfl_xor(s[c][i], off, 64);
  }
  if (tx == 0) {
#pragma unroll
    for (int i = 0; i < 2; ++i) {
      int o = o0 + (ty << 1) + i;
      if (o < 341) {
#pragma unroll
        for (int c = 0; c < 3; ++c)
          part[(((size_t)b * 341 + o) * 3 + c) * NT + blockIdx.x] = s[c][i];
      }
    }
  }
}

__global__ void final_reduce_kernel(const float* __restrict__ part,
                                    float* __restrict__ out) {
  int t = blockIdx.x * 256 + threadIdx.x;
  if (t >= BB * 341 * 3) return;
  const float* p = part + (size_t)t * NT;
  float s = 0.f;
#pragma unroll
  for (int nt = 0; nt < NT; ++nt) s += p[nt];
  out[t] = s * (1.f / 1024.f);
}

extern "C" void kernel_launch(void* const* d_in, const int* in_sizes, int n_in,
                              void* d_out, int out_size, void* d_ws,
                              size_t ws_size, hipStream_t stream) {
  (void)in_sizes; (void)n_in; (void)out_size; (void)ws_size;
  const float* x = (const float*)d_in[0];
  const float* Wf[5] = {(const float*)d_in[1], (const float*)d_in[3],
                        (const float*)d_in[5], (const float*)d_in[7],
                        (const float*)d_in[9]};
  const float* Wd[5] = {(const float*)d_in[2], (const float*)d_in[4],
                        (const float*)d_in[6], (const float*)d_in[8],
                        (const float*)d_in[10]};

  float* ws = (float*)d_ws;
  float* dist = ws;
  float* part = ws;  // dist region dead once final_fused runs
  // ubuf/vbuf overlay the dist region too (dist dead after topk each layer):
  // 2 x BB*85*3072 float2 = 8.35M floats <= 8.39M-float dist region.
  float2* ubuf = (float2*)ws;
  float2* vbuf = (float2*)(ws + (size_t)BB * 85 * 3072 * 2);
  size_t off = (size_t)BB * NN * NN;
  int* idx = (int*)(ws + off);
  off += (size_t)BB * NN * KK;
  float* xcat = ws + off;

  struct LayerCfg { int D, Co, inoff, ooff, nsplit; };
  const LayerCfg L[4] = {
      {1, 21, 0, 0, 4},
      {21, 21, 0, 21, 4},
      {21, 42, 21, 42, 2},
      {42, 85, 42, 84, 2},
  };

  for (int l = 0; l < 4; ++l) {
    const float* src = (l == 0) ? x : (xcat + (size_t)L[l].inoff * 3 * NN);
    int bs = (l == 0) ? 3 * NN : CCAT * 3 * NN;
    int D = L[l].D, Co = L[l].Co;

    dist_tile_kernel<<<dim3(36, 1, BB), 256, 0, stream>>>(src, bs, 3 * D, dist);
    topk_kernel<<<(BB * NN) / 4, 256, 0, stream>>>(dist, idx);
    transform_kernel<<<dim3(24, (Co + 15) / 16, BB), 256, 0, stream>>>(
        src, bs, D, Co, Wf[l], Wd[l], ubuf, vbuf);
    gather_kernel<<<dim3(BB * Co, L[l].nsplit), 256, 0, stream>>>(
        ubuf, vbuf, Co, L[l].nsplit, idx, L[l].ooff, xcat);
  }

  final_fused_kernel<<<dim3(NT, 11, BB), 256, 0, stream>>>(xcat, Wf[4], Wd[4],
                                                           part);
  final_reduce_kernel<<<(BB * 341 * 3 + 255) / 256, 256, 0, stream>>>(
      part, (float*)d_out);
}

// Round 8
// 428.710 us; speedup vs baseline: 1.1451x; 1.1451x over previous
//
#include <hip/hip_runtime.h>
#include <cstddef>

#define BB 8
#define NN 1024
#define KK 20
#define CCAT 169
#define NT 16  // n-tiles of 64 in final fused GEMM

// ---------------- neg dist, symmetric triangle tiles, norms fused in --------
// dist[b][n][m] = 2*sum_f x[f][n]*x[f][m] - ||x_n||^2 - ||x_m||^2  (symmetric)
__global__ __launch_bounds__(256) void dist_tile_kernel(
    const float* __restrict__ src, int bs, int F, float* __restrict__ dist) {
  __shared__ float As[8][128];
  __shared__ float Bs[8][128];
  int b = blockIdx.z;
  int rem = blockIdx.x, bi = 0;
  while (rem >= 8 - bi) { rem -= 8 - bi; ++bi; }
  int bj = bi + rem;
  int n0 = bi * 128;
  int m0 = bj * 128;
  int t = threadIdx.x;
  int tx = t & 15, ty = t >> 4;
  const float* p = src + (size_t)b * bs;

  float acc[8][8];
  float xn[8], xm[8];
#pragma unroll
  for (int i = 0; i < 8; ++i) {
    xn[i] = 0.f;
    xm[i] = 0.f;
#pragma unroll
    for (int j = 0; j < 8; ++j) acc[i][j] = 0.f;
  }

  int fr = t >> 5;
  int cc = (t & 31) << 2;
  for (int f0 = 0; f0 < F; f0 += 8) {
    int f = f0 + fr;
    float4 av = {0.f, 0.f, 0.f, 0.f}, bv = {0.f, 0.f, 0.f, 0.f};
    if (f < F) {
      av = *(const float4*)(p + (size_t)f * NN + n0 + cc);
      bv = *(const float4*)(p + (size_t)f * NN + m0 + cc);
    }
    __syncthreads();
    *(float4*)&As[fr][cc] = av;
    *(float4*)&Bs[fr][cc] = bv;
    __syncthreads();
#pragma unroll
    for (int f2 = 0; f2 < 8; ++f2) {
      float4 al = *(const float4*)&As[f2][ty << 2];
      float4 ah = *(const float4*)&As[f2][64 + (ty << 2)];
      float4 bl = *(const float4*)&Bs[f2][tx << 2];
      float4 bh = *(const float4*)&Bs[f2][64 + (tx << 2)];
      float a[8] = {al.x, al.y, al.z, al.w, ah.x, ah.y, ah.z, ah.w};
      float bb[8] = {bl.x, bl.y, bl.z, bl.w, bh.x, bh.y, bh.z, bh.w};
#pragma unroll
      for (int i = 0; i < 8; ++i) xn[i] += a[i] * a[i];
#pragma unroll
      for (int j = 0; j < 8; ++j) xm[j] += bb[j] * bb[j];
#pragma unroll
      for (int i = 0; i < 8; ++i)
#pragma unroll
        for (int j = 0; j < 8; ++j) acc[i][j] += a[i] * bb[j];
    }
  }

#pragma unroll
  for (int i = 0; i < 8; ++i)
#pragma unroll
    for (int j = 0; j < 8; ++j) acc[i][j] = 2.f * acc[i][j] - xn[i] - xm[j];

#pragma unroll
  for (int i = 0; i < 8; ++i) {
    int n = n0 + ((i < 4) ? ((ty << 2) + i) : (64 + (ty << 2) + i - 4));
    float* dr = dist + (((size_t)b * NN + n) << 10);
    *(float4*)(dr + m0 + (tx << 2)) =
        make_float4(acc[i][0], acc[i][1], acc[i][2], acc[i][3]);
    *(float4*)(dr + m0 + 64 + (tx << 2)) =
        make_float4(acc[i][4], acc[i][5], acc[i][6], acc[i][7]);
  }

  if (bi != bj) {
#pragma unroll
    for (int j = 0; j < 8; ++j) {
      int m = m0 + ((j < 4) ? ((tx << 2) + j) : (64 + (tx << 2) + j - 4));
      float* dr = dist + (((size_t)b * NN + m) << 10);
      *(float4*)(dr + n0 + (ty << 2)) =
          make_float4(acc[0][j], acc[1][j], acc[2][j], acc[3][j]);
      *(float4*)(dr + n0 + 64 + (ty << 2)) =
          make_float4(acc[4][j], acc[5][j], acc[6][j], acc[7][j]);
    }
  }
}

// ---------------- top-k (k=20) per row, one wave per row ----------------
__device__ __forceinline__ unsigned long long shfl_xor_u64(
    unsigned long long v, int off) {
  unsigned lo = (unsigned)v, hi = (unsigned)(v >> 32);
  lo = __shfl_xor(lo, off, 64);
  hi = __shfl_xor(hi, off, 64);
  return ((unsigned long long)hi << 32) | lo;
}

__global__ __launch_bounds__(256) void topk_kernel(
    const float* __restrict__ dist, int* __restrict__ idx_out) {
  int wave = threadIdx.x >> 6;
  int lane = threadIdx.x & 63;
  int row = blockIdx.x * 4 + wave;
  const float* d = dist + ((size_t)row << 10);

  unsigned long long key[16];
#pragma unroll
  for (int s = 0; s < 16; ++s) {
    int m = lane + (s << 6);
    unsigned u = __float_as_uint(d[m]);
    u = (u & 0x80000000u) ? ~u : (u | 0x80000000u);
    key[s] = ((unsigned long long)u << 32) | (unsigned)(NN - 1 - m);
  }

#pragma unroll
  for (int size = 2; size <= 16; size <<= 1) {
#pragma unroll
    for (int stride = size >> 1; stride > 0; stride >>= 1) {
#pragma unroll
      for (int i = 0; i < 16; ++i) {
        int j = i ^ stride;
        if (j > i) {
          unsigned long long a = key[i], c = key[j];
          bool desc = ((i & size) == 0);
          bool sw = desc ? (a < c) : (a > c);
          key[i] = sw ? c : a;
          key[j] = sw ? a : c;
        }
      }
    }
  }

  int* out = idx_out + row * KK;
  unsigned long long head = key[0];
  for (int r = 0; r < KK; ++r) {
    unsigned long long w = head;
#pragma unroll
    for (int off = 32; off > 0; off >>= 1) {
      unsigned long long o = shfl_xor_u64(w, off);
      if (o > w) w = o;
    }
    if (lane == 0) out[r] = (NN - 1) - (int)(w & 0xFFFFFFFFull);
    if (head == w) {
#pragma unroll
      for (int s = 0; s < 15; ++s) key[s] = key[s + 1];
      key[15] = 0ull;
      head = key[0];
    }
  }
}

// ---------------- fused transform + edge combine + mean over k --------------
// R6 structure (256 threads, n-split), with phase A templated on D:
// compile-time trip count + interleaved r-groups + unroll(2) keeps 6
// independent global loads in flight (runtime-D loop had ~1). Accumulation
// order over i unchanged -> bitwise-identical xcat.
template <int DD>
__global__ __launch_bounds__(256) void edge_fused_kernel(
    const float* __restrict__ src, int bs, int Co, int nsplit,
    const float* __restrict__ Wf, const float* __restrict__ Wd,
    const int* __restrict__ idx, int ooff, float* __restrict__ xcat) {
  __shared__ float2 Ulds[3 * NN];  // 24 KB {Uf,Ud}
  __shared__ float2 Vlds[3 * NN];  // 24 KB {Vf,Vd}
  __shared__ float4 Wlds[48];      // {wfa, wfb, wda, wdb} per i, DD<=42
  int bo = blockIdx.x;
  int b = bo / Co, o = bo % Co;
  int t = threadIdx.x;

  if (t < DD) {
    float wfa = Wf[o * 2 * DD + t];
    float wfb = Wf[o * 2 * DD + DD + t] - wfa;
    float wda = Wd[o * 2 * DD + t];
    float wdb = Wd[o * 2 * DD + DD + t] - wda;
    Wlds[t] = make_float4(wfa, wfb, wda, wdb);
  }
  __syncthreads();

  const float* sb = src + (size_t)b * bs;
  // phase A: thread t owns columns c0..c0+3 of each of the 3 r-groups
  {
    int c0 = t << 2;
    float4 uf[3], vf[3], ud[3], vd[3];
#pragma unroll
    for (int r = 0; r < 3; ++r) {
      uf[r] = make_float4(0.f, 0.f, 0.f, 0.f);
      vf[r] = make_float4(0.f, 0.f, 0.f, 0.f);
      ud[r] = make_float4(0.f, 0.f, 0.f, 0.f);
      vd[r] = make_float4(0.f, 0.f, 0.f, 0.f);
    }
#pragma unroll 2
    for (int i = 0; i < DD; ++i) {
      const float* row = sb + (size_t)i * 3 * NN + c0;
      float4 s[3];
      s[0] = *(const float4*)(row);
      s[1] = *(const float4*)(row + 1024);
      s[2] = *(const float4*)(row + 2048);
      float4 w = Wlds[i];
#pragma unroll
      for (int r = 0; r < 3; ++r) {
        uf[r].x += w.x * s[r].x; uf[r].y += w.x * s[r].y;
        uf[r].z += w.x * s[r].z; uf[r].w += w.x * s[r].w;
        vf[r].x += w.y * s[r].x; vf[r].y += w.y * s[r].y;
        vf[r].z += w.y * s[r].z; vf[r].w += w.y * s[r].w;
        ud[r].x += w.z * s[r].x; ud[r].y += w.z * s[r].y;
        ud[r].z += w.z * s[r].z; ud[r].w += w.z * s[r].w;
        vd[r].x += w.w * s[r].x; vd[r].y += w.w * s[r].y;
        vd[r].z += w.w * s[r].z; vd[r].w += w.w * s[r].w;
      }
    }
#pragma unroll
    for (int r = 0; r < 3; ++r) {
      int g = t + 256 * r;
      *(float4*)&Ulds[(g << 2) + 0] =
          make_float4(uf[r].x, ud[r].x, uf[r].y, ud[r].y);
      *(float4*)&Ulds[(g << 2) + 2] =
          make_float4(uf[r].z, ud[r].z, uf[r].w, ud[r].w);
      *(float4*)&Vlds[(g << 2) + 0] =
          make_float4(vf[r].x, vd[r].x, vf[r].y, vd[r].y);
      *(float4*)&Vlds[(g << 2) + 2] =
          make_float4(vf[r].z, vd[r].z, vf[r].w, vd[r].w);
    }
  }
  __syncthreads();

  const float inv_k = 1.f / KK;
  // phase B: this block's n-slice
  int cnt = NN / nsplit;
  int nbase = blockIdx.y * cnt;
  for (int n = nbase + t; n < nbase + cnt; n += 256) {
    float2 v0 = Vlds[n];
    float2 v1 = Vlds[NN + n];
    float2 v2 = Vlds[2 * NN + n];
    const int4* ip = (const int4*)(idx + (b * NN + n) * KK);
    float a0 = 0.f, a1 = 0.f, a2 = 0.f;
#pragma unroll
    for (int q = 0; q < 5; ++q) {
      int4 iv = ip[q];
      int nbs[4] = {iv.x, iv.y, iv.z, iv.w};
#pragma unroll
      for (int jj = 0; jj < 4; ++jj) {
        int nb = nbs[jj];
        float2 u0 = Ulds[nb];
        float2 u1 = Ulds[NN + nb];
        float2 u2 = Ulds[2 * NN + nb];
        float pf0 = u0.x + v0.x, pd0 = u0.y + v0.y;
        float pf1 = u1.x + v1.x, pd1 = u1.y + v1.y;
        float pf2 = u2.x + v2.x, pd2 = u2.y + v2.y;
        float dot = pf0 * pd0 + pf1 * pd1 + pf2 * pd2;
        float dsq = pd0 * pd0 + pd1 * pd1 + pd2 * pd2;
        float g = (dot >= 0.f) ? 0.f : 0.8f * dot / (dsq + 1e-6f);
        a0 += pf0 - g * pd0;
        a1 += pf1 - g * pd1;
        a2 += pf2 - g * pd2;
      }
    }
    size_t ob = (size_t)b * CCAT * 3 * NN + (size_t)(ooff + o) * 3 * NN + n;
    xcat[ob] = a0 * inv_k;
    xcat[ob + NN] = a1 * inv_k;
    xcat[ob + 2 * NN] = a2 * inv_k;
  }
}

// ---------------- fused final GEMM + dvec + VN-leakyrelu + partial n-sum ----
// R0 version verbatim: 256 threads, BK=16, two-barrier loop. 73 µs, VGPR 120.
// (512-thread variants spilled R3-R5; o-tile-32 variant regressed R7.)
__global__ __launch_bounds__(256) void final_fused_kernel(
    const float* __restrict__ xcat, const float* __restrict__ Wf4,
    const float* __restrict__ Wd4, float* __restrict__ part) {
  __shared__ float Ws[16][64];
  __shared__ float Xs[3][16][64];
  __shared__ float Wds[16];
  int b = blockIdx.z;
  int o0 = blockIdx.y * 64;
  int n0 = blockIdx.x * 64;
  int t = threadIdx.x;
  int tx = t & 15, ty = t >> 4;

  float acc[3][4][4];  // [c][o_i][n_j]
  float dv[3][4];      // [c][n_j]
#pragma unroll
  for (int c = 0; c < 3; ++c) {
#pragma unroll
    for (int i = 0; i < 4; ++i)
#pragma unroll
      for (int j = 0; j < 4; ++j) acc[c][i][j] = 0.f;
#pragma unroll
    for (int j = 0; j < 4; ++j) dv[c][j] = 0.f;
  }

  const float* xb = xcat + (size_t)b * CCAT * 3 * NN;
  for (int f0 = 0; f0 < CCAT; f0 += 16) {
    int f = f0 + ty;
    float4 xv[3];
#pragma unroll
    for (int c = 0; c < 3; ++c) {
      xv[c] = make_float4(0.f, 0.f, 0.f, 0.f);
      if (f < CCAT)
        xv[c] = *(const float4*)(xb + ((size_t)f * 3 + c) * NN + n0 + (tx << 2));
    }
    float wv[4];
#pragma unroll
    for (int q = 0; q < 4; ++q) {
      int o = o0 + (tx << 2) + q;
      wv[q] = (o < 341 && f < CCAT) ? Wf4[o * CCAT + f] : 0.f;
    }
    float wdv = 0.f;
    if (t < 16 && f0 + t < CCAT) wdv = Wd4[f0 + t];
    __syncthreads();
#pragma unroll
    for (int c = 0; c < 3; ++c) *(float4*)&Xs[c][ty][tx << 2] = xv[c];
    *(float4*)&Ws[ty][tx << 2] = make_float4(wv[0], wv[1], wv[2], wv[3]);
    if (t < 16) Wds[t] = wdv;
    __syncthreads();
#pragma unroll
    for (int f2 = 0; f2 < 16; ++f2) {
      float4 w = *(const float4*)&Ws[f2][ty << 2];
      float wa[4] = {w.x, w.y, w.z, w.w};
      float wd = Wds[f2];
#pragma unroll
      for (int c = 0; c < 3; ++c) {
        float4 x = *(const float4*)&Xs[c][f2][tx << 2];
        float xa[4] = {x.x, x.y, x.z, x.w};
#pragma unroll
        for (int j = 0; j < 4; ++j) dv[c][j] += wd * xa[j];
#pragma unroll
        for (int i = 0; i < 4; ++i)
#pragma unroll
          for (int j = 0; j < 4; ++j) acc[c][i][j] += wa[i] * xa[j];
      }
    }
  }

  float s[3][4];
#pragma unroll
  for (int c = 0; c < 3; ++c)
#pragma unroll
    for (int i = 0; i < 4; ++i) s[c][i] = 0.f;
#pragma unroll
  for (int i = 0; i < 4; ++i) {
#pragma unroll
    for (int j = 0; j < 4; ++j) {
      float d0 = dv[0][j], d1 = dv[1][j], d2 = dv[2][j];
      float p0 = acc[0][i][j], p1 = acc[1][i][j], p2 = acc[2][i][j];
      float dot = p0 * d0 + p1 * d1 + p2 * d2;
      float dsq = d0 * d0 + d1 * d1 + d2 * d2;
      float g = (dot >= 0.f) ? 0.f : 0.8f * dot / (dsq + 1e-6f);
      s[0][i] += p0 - g * d0;
      s[1][i] += p1 - g * d1;
      s[2][i] += p2 - g * d2;
    }
  }

#pragma unroll
  for (int off = 1; off < 16; off <<= 1) {
#pragma unroll
    for (int c = 0; c < 3; ++c)
#pragma unroll
      for (int i = 0; i < 4; ++i) s[c][i] += __shfl_xor(s[c][i], off, 64);
  }
  if (tx == 0) {
#pragma unroll
    for (int i = 0; i < 4; ++i) {
      int o = o0 + (ty << 2) + i;
      if (o < 341) {
#pragma unroll
        for (int c = 0; c < 3; ++c)
          part[(((size_t)b * 341 + o) * 3 + c) * NT + blockIdx.x] = s[c][i];
      }
    }
  }
}

__global__ void final_reduce_kernel(const float* __restrict__ part,
                                    float* __restrict__ out) {
  int t = blockIdx.x * 256 + threadIdx.x;
  if (t >= BB * 341 * 3) return;
  const float* p = part + (size_t)t * NT;
  float s = 0.f;
#pragma unroll
  for (int nt = 0; nt < NT; ++nt) s += p[nt];
  out[t] = s * (1.f / 1024.f);
}

extern "C" void kernel_launch(void* const* d_in, const int* in_sizes, int n_in,
                              void* d_out, int out_size, void* d_ws,
                              size_t ws_size, hipStream_t stream) {
  (void)in_sizes; (void)n_in; (void)out_size; (void)ws_size;
  const float* x = (const float*)d_in[0];
  const float* Wf[5] = {(const float*)d_in[1], (const float*)d_in[3],
                        (const float*)d_in[5], (const float*)d_in[7],
                        (const float*)d_in[9]};
  const float* Wd[5] = {(const float*)d_in[2], (const float*)d_in[4],
                        (const float*)d_in[6], (const float*)d_in[8],
                        (const float*)d_in[10]};

  float* ws = (float*)d_ws;
  float* dist = ws;
  float* part = ws;  // dist region dead once final_fused runs
  size_t off = (size_t)BB * NN * NN;
  int* idx = (int*)(ws + off);
  off += (size_t)BB * NN * KK;
  float* xcat = ws + off;

  struct LayerCfg { int D, Co, inoff, ooff, nsplit; };
  const LayerCfg L[4] = {
      {1, 21, 0, 0, 4},
      {21, 21, 0, 21, 4},
      {21, 42, 21, 42, 2},
      {42, 85, 42, 84, 1},
  };

  for (int l = 0; l < 4; ++l) {
    const float* src = (l == 0) ? x : (xcat + (size_t)L[l].inoff * 3 * NN);
    int bs = (l == 0) ? 3 * NN : CCAT * 3 * NN;
    int D = L[l].D, Co = L[l].Co;

    dist_tile_kernel<<<dim3(36, 1, BB), 256, 0, stream>>>(src, bs, 3 * D, dist);
    topk_kernel<<<(BB * NN) / 4, 256, 0, stream>>>(dist, idx);
    dim3 eg(BB * Co, L[l].nsplit);
    if (D == 1)
      edge_fused_kernel<1><<<eg, 256, 0, stream>>>(
          src, bs, Co, L[l].nsplit, Wf[l], Wd[l], idx, L[l].ooff, xcat);
    else if (D == 21)
      edge_fused_kernel<21><<<eg, 256, 0, stream>>>(
          src, bs, Co, L[l].nsplit, Wf[l], Wd[l], idx, L[l].ooff, xcat);
    else
      edge_fused_kernel<42><<<eg, 256, 0, stream>>>(
          src, bs, Co, L[l].nsplit, Wf[l], Wd[l], idx, L[l].ooff, xcat);
  }

  final_fused_kernel<<<dim3(NT, 6, BB), 256, 0, stream>>>(xcat, Wf[4], Wd[4],
                                                          part);
  final_reduce_kernel<<<(BB * 341 * 3 + 255) / 256, 256, 0, stream>>>(
      part, (float*)d_out);
}